// Round 7
// baseline (457.173 us; speedup 1.0000x reference)
//
#include <hip/hip_runtime.h>

// Walsh-Hadamard (n=4096) per row + affine epilogue: out = scale*(H x)/64 + shift
// v7: v6's structure (256 thr, 17 KB LDS, swizzle middle stage, 1 barrier/row,
//     256B/instr nt stores, 8 blocks/CU) with TWO ROWS PER BLOCK, both loaded
//     at block start -> 8 float4 loads in flight (2x MLP, 32 KB/block),
//     grid halves to 8192. Rows share the single LDS buffer sequentially;
//     row B's register work (wht16+swizzles) overlaps row A's barrier wait.
//
// Occupancy ledger (the v2-v5 lesson: never pay occupancy for overlap):
//   LDS 17408 B (unchanged), VGPR ~= 32 data + ~16 overhead < 64, pinned by
//   __launch_bounds__(256, 8) -> still 8 blocks/CU = 32 waves/CU.
//
// Index algebra per row (elem e = 16t + j):
//   digit j (bits 0-3):  wht16 in registers after 4x float4 load.
//   digit m = lane&15 (bits 4-7): ds_swizzle xor butterflies (h=1,2,4,8),
//     v' = fmaf(sgn, v, partner) with sgn = (lane&h ? -1 : +1).
//   digit g = t>>4 (bits 8-11): one LDS transpose (pad-17: write 2-way free,
//     read 3-way minor), then wht16 in registers.
// Final ownership e(r) = 256r + t -> per-instr 256 contiguous bytes ->
// nt dword stores are amplification-free (v3-verified; v5 showed 64B-granule
// nt patterns amplify 1.2x -- avoided).

#define ROW 4096
#define STR 17  // padded LDS row stride (words)

__device__ __forceinline__ void wht16(float v[16]) {
#pragma unroll
  for (int h = 1; h < 16; h <<= 1) {
#pragma unroll
    for (int i = 0; i < 16; ++i) {
      if ((i & h) == 0) {
        float a = v[i], b = v[i | h];
        v[i] = a + b;
        v[i | h] = a - b;
      }
    }
  }
}

template <int PAT>
__device__ __forceinline__ void swz_step(float v[16], float sgn) {
#pragma unroll
  for (int j = 0; j < 16; ++j) {
    const int pi = __builtin_amdgcn_ds_swizzle(__float_as_int(v[j]), PAT);
    v[j] = fmaf(sgn, v[j], __int_as_float(pi));
  }
}

// middle digit m = lane&15: butterfly over lane bits 1,2,4,8 (BitMode xor)
__device__ __forceinline__ void swz_mid(float v[16], int lane) {
  swz_step<0x041F>(v, (lane & 1) ? -1.f : 1.f);
  swz_step<0x081F>(v, (lane & 2) ? -1.f : 1.f);
  swz_step<0x101F>(v, (lane & 4) ? -1.f : 1.f);
  swz_step<0x201F>(v, (lane & 8) ? -1.f : 1.f);
}

__global__ __launch_bounds__(256, 8) void AdaptiveHadamardTransform_kernel(
    const float* __restrict__ x, const float* __restrict__ scale,
    const float* __restrict__ shift, float* __restrict__ out) {
  __shared__ float lds[256 * STR];  // 17408 B -> thread-limited 8 blocks/CU

  const int t = threadIdx.x;
  const int lane = t & 63;
  const long long baseA = (long long)blockIdx.x * (2 * ROW);
  const long long baseB = baseA + ROW;

  float a[16], b[16];

  // ---- load BOTH rows up front: 8x float4 in flight (32 KB/block MLP).
  {
    const float4* __restrict__ a4 =
        reinterpret_cast<const float4*>(x + baseA + 16 * t);
    const float4* __restrict__ b4 =
        reinterpret_cast<const float4*>(x + baseB + 16 * t);
#pragma unroll
    for (int q = 0; q < 4; ++q) {
      const float4 f = a4[q];
      a[4 * q + 0] = f.x;
      a[4 * q + 1] = f.y;
      a[4 * q + 2] = f.z;
      a[4 * q + 3] = f.w;
    }
#pragma unroll
    for (int q = 0; q < 4; ++q) {
      const float4 f = b4[q];
      b[4 * q + 0] = f.x;
      b[4 * q + 1] = f.y;
      b[4 * q + 2] = f.z;
      b[4 * q + 3] = f.w;
    }
  }

  const float norm = 0.015625f;  // 1/sqrt(4096)
  const int i1 = t >> 4, i0 = t & 15;

  // ======== row A ========
  wht16(a);          // digit j
  swz_mid(a, lane);  // digit m
#pragma unroll
  for (int j = 0; j < 16; ++j) lds[t * STR + j] = a[j];  // 2-way, free

  // row B's register-side work overlaps other waves' writes + barrier skew
  wht16(b);          // digit j
  swz_mid(b, lane);  // digit m

  __syncthreads();

#pragma unroll
  for (int r = 0; r < 16; ++r) a[r] = lds[(r * 16 + i1) * STR + i0];  // 3-way
  wht16(a);  // digit g
#pragma unroll
  for (int r = 0; r < 16; ++r) {
    const int c = r * 256 + t;  // 256 contiguous B per store instr
    const float o = fmaf(scale[c], a[r] * norm, shift[c]);
    __builtin_nontemporal_store(o, out + baseA + c);
  }

  __syncthreads();  // WAR: all row-A reads done before row-B writes

  // ======== row B ========
#pragma unroll
  for (int j = 0; j < 16; ++j) lds[t * STR + j] = b[j];
  __syncthreads();

#pragma unroll
  for (int r = 0; r < 16; ++r) b[r] = lds[(r * 16 + i1) * STR + i0];
  wht16(b);  // digit g
#pragma unroll
  for (int r = 0; r < 16; ++r) {
    const int c = r * 256 + t;
    const float o = fmaf(scale[c], b[r] * norm, shift[c]);
    __builtin_nontemporal_store(o, out + baseB + c);
  }
}

extern "C" void kernel_launch(void* const* d_in, const int* in_sizes, int n_in,
                              void* d_out, int out_size, void* d_ws, size_t ws_size,
                              hipStream_t stream) {
  const float* x = (const float*)d_in[0];
  const float* scale = (const float*)d_in[1];
  const float* shift = (const float*)d_in[2];
  float* out = (float*)d_out;

  const int rows = in_sizes[0] / ROW;  // 16384, even
  AdaptiveHadamardTransform_kernel<<<rows / 2, 256, 0, stream>>>(x, scale, shift, out);
}

// Round 9
// 443.662 us; speedup vs baseline: 1.0305x; 1.0305x over previous
//
#include <hip/hip_runtime.h>

// Walsh-Hadamard (n=4096) per row + affine epilogue: out = scale*(H x)/64 + shift
// v8: v6 champion structure + 2 rows/block with PINNED row-B prefetch.
//
// v7 post-mortem: loading both rows up front was undone by the compiler
// (VGPR_Count=32 proves a[16]+b[16] were never simultaneously live; it sank
// the B loads past row-A processing -> FETCH +16MB from L3 aging, no MLP
// gain, 172 us). v8 pins the B loads with sched_barrier(0) so they ISSUE
// between row A's LDS write and the barrier -> B's 16 KB HBM latency+BW
// hides under A's back half (LDS transpose + wht16 + scale/shift loads +
// 16 nt stores). Peak live = b[16] + a[16] + temps ~= 56 < 64 -> still
// 8 blocks/CU (32 waves/CU), the residency that v2-v5 proved mandatory.
//
// Per-row algebra (elem e = 16t + j) — unchanged from v6:
//   digit j (bits 0-3): wht16 in regs after 4x float4 load.
//   digit m = lane&15 (bits 4-7): ds_swizzle xor butterflies h=1,2,4,8,
//     v' = fmaf(sgn, v, partner).
//   digit g = t>>4 (bits 8-11): one pad-17 LDS transpose (write 2-way free,
//     read 3-way minor), wht16 in regs.
// Final ownership e(r) = 256r + t -> 256 contiguous B per store instr ->
// nt dword stores amplification-free (v3-verified; 64B-granule nt patterns
// amplify 1.2x — avoided).

#define ROW 4096
#define STR 17  // padded LDS row stride (words)

__device__ __forceinline__ void wht16(float v[16]) {
#pragma unroll
  for (int h = 1; h < 16; h <<= 1) {
#pragma unroll
    for (int i = 0; i < 16; ++i) {
      if ((i & h) == 0) {
        float a = v[i], b = v[i | h];
        v[i] = a + b;
        v[i | h] = a - b;
      }
    }
  }
}

template <int PAT>
__device__ __forceinline__ void swz_step(float v[16], float sgn) {
#pragma unroll
  for (int j = 0; j < 16; ++j) {
    const int pi = __builtin_amdgcn_ds_swizzle(__float_as_int(v[j]), PAT);
    v[j] = fmaf(sgn, v[j], __int_as_float(pi));
  }
}

// middle digit m = lane&15: butterflies over lane bits 1,2,4,8 (BitMode xor)
__device__ __forceinline__ void swz_mid(float v[16], int lane) {
  swz_step<0x041F>(v, (lane & 1) ? -1.f : 1.f);
  swz_step<0x081F>(v, (lane & 2) ? -1.f : 1.f);
  swz_step<0x101F>(v, (lane & 4) ? -1.f : 1.f);
  swz_step<0x201F>(v, (lane & 8) ? -1.f : 1.f);
}

__global__ __launch_bounds__(256, 8) void AdaptiveHadamardTransform_kernel(
    const float* __restrict__ x, const float* __restrict__ scale,
    const float* __restrict__ shift, float* __restrict__ out) {
  __shared__ float lds[256 * STR];  // 17408 B -> 8 blocks/CU

  const int t = threadIdx.x;
  const int lane = t & 63;
  const long long baseA = (long long)blockIdx.x * (2 * ROW);
  const long long baseB = baseA + ROW;
  const float norm = 0.015625f;  // 1/sqrt(4096)
  const int i1 = t >> 4, i0 = t & 15;

  float a[16], b[16];

  // ======== row A front half ========
  {
    const float4* __restrict__ a4 =
        reinterpret_cast<const float4*>(x + baseA + 16 * t);
#pragma unroll
    for (int q = 0; q < 4; ++q) {
      const float4 f = a4[q];
      a[4 * q + 0] = f.x;
      a[4 * q + 1] = f.y;
      a[4 * q + 2] = f.z;
      a[4 * q + 3] = f.w;
    }
  }
  wht16(a);          // digit j
  swz_mid(a, lane);  // digit m
#pragma unroll
  for (int j = 0; j < 16; ++j) lds[t * STR + j] = a[j];  // 2-way, free

  // ---- PINNED row-B load: issues HERE (sched_barrier stops the compiler
  // from sinking it past the barrier like it did in v7). Flies under row A's
  // entire back half.
  {
    const float4* __restrict__ b4 =
        reinterpret_cast<const float4*>(x + baseB + 16 * t);
#pragma unroll
    for (int q = 0; q < 4; ++q) {
      const float4 f = b4[q];
      b[4 * q + 0] = f.x;
      b[4 * q + 1] = f.y;
      b[4 * q + 2] = f.z;
      b[4 * q + 3] = f.w;
    }
  }
  __builtin_amdgcn_sched_barrier(0);

  __syncthreads();

  // ======== row A back half ========
#pragma unroll
  for (int r = 0; r < 16; ++r) a[r] = lds[(r * 16 + i1) * STR + i0];  // 3-way
  wht16(a);  // digit g
#pragma unroll
  for (int r = 0; r < 16; ++r) {
    const int c = r * 256 + t;  // 256 contiguous B per store instr
    const float o = fmaf(scale[c], a[r] * norm, shift[c]);
    __builtin_nontemporal_store(o, out + baseA + c);
  }

  __syncthreads();  // WAR: all row-A LDS reads done before row-B writes

  // ======== row B ========
  wht16(b);          // digit j
  swz_mid(b, lane);  // digit m
#pragma unroll
  for (int j = 0; j < 16; ++j) lds[t * STR + j] = b[j];
  __syncthreads();

#pragma unroll
  for (int r = 0; r < 16; ++r) b[r] = lds[(r * 16 + i1) * STR + i0];
  wht16(b);  // digit g
#pragma unroll
  for (int r = 0; r < 16; ++r) {
    const int c = r * 256 + t;
    const float o = fmaf(scale[c], b[r] * norm, shift[c]);
    __builtin_nontemporal_store(o, out + baseB + c);
  }
}

extern "C" void kernel_launch(void* const* d_in, const int* in_sizes, int n_in,
                              void* d_out, int out_size, void* d_ws, size_t ws_size,
                              hipStream_t stream) {
  const float* x = (const float*)d_in[0];
  const float* scale = (const float*)d_in[1];
  const float* shift = (const float*)d_in[2];
  float* out = (float*)d_out;

  const int rows = in_sizes[0] / ROW;  // 16384, even
  AdaptiveHadamardTransform_kernel<<<rows / 2, 256, 0, stream>>>(x, scale, shift, out);
}